// Round 1
// baseline (341.816 us; speedup 1.0000x reference)
//
#include <hip/hip_runtime.h>

typedef __bf16 bf16;
typedef float f32x4 __attribute__((ext_vector_type(4)));
typedef bf16 bf16x8 __attribute__((ext_vector_type(8)));
typedef bf16 bf16x4 __attribute__((ext_vector_type(4)));

#define NB 4
#define NQ 384
#define NK 384
#define DE 64
#define DQI 256
#define DFF 256
#define DMSG 64
#define DOUT 64
#define KEXT 160  // 128 feature-k + 32 one-hot bias k

// ws layout (bytes)
#define WS_AQ 0
#define WS_AK 1572864
#define WS_W1T 3145728
#define WS_W2T 3211264

__global__ __launch_bounds__(256) void prep_kernel(
    const float* __restrict__ q_inv, const float* __restrict__ k_inv,
    const float* __restrict__ Wq, const float* __restrict__ bq,
    const float* __restrict__ Wk, const float* __restrict__ bk,
    const float* __restrict__ W1, const float* __restrict__ b1,
    const float* __restrict__ W2,
    float* __restrict__ Aq, float* __restrict__ Ak,
    bf16* __restrict__ w1t, bf16* __restrict__ w2t)
{
  const int t = threadIdx.x;
  const int bid = blockIdx.x;
  if (bid < 2 * NB * NQ) {
    __shared__ float sin_[DQI];
    __shared__ float smsg[DMSG];
    const bool isQ = bid < NB * NQ;
    const int row = isQ ? bid : bid - NB * NQ;  // b*N + idx
    const float* inv = isQ ? q_inv : k_inv;
    const float* Wm = isQ ? Wq : Wk;
    const float* bm = isQ ? bq : bk;
    sin_[t] = inv[row * DQI + t];
    __syncthreads();
    if (t < DMSG) {
      float acc = bm[t];
#pragma unroll 8
      for (int d = 0; d < DQI; ++d) acc += sin_[d] * Wm[d * DMSG + t];
      smsg[t] = acc;
    }
    __syncthreads();
    {
      float acc = isQ ? b1[t] : 0.f;
      const float* w1rows = W1 + (isQ ? 0 : DMSG * DFF);
#pragma unroll 8
      for (int e = 0; e < DMSG; ++e) acc += smsg[e] * w1rows[e * DFF + t];
      (isQ ? Aq : Ak)[row * DFF + t] = acc;
    }
  } else if (bid == 2 * NB * NQ) {
    // w1t[cs][k] = bf16(W1[128+k][c(cs)]), row-permuted c
    const int cs = t;
    const int c = ((cs >> 5) << 5) + (((cs >> 4) & 1) << 2) + (((cs >> 2) & 3) << 3) + (cs & 3);
    for (int k8 = 0; k8 < 16; ++k8) {
      bf16x8 v;
#pragma unroll
      for (int j = 0; j < 8; ++j) {
        int k = k8 * 8 + j;
        v[j] = (bf16)W1[(128 + k) * DFF + c];
      }
      *(bf16x8*)&w1t[cs * 128 + k8 * 8] = v;
    }
  } else {
    // w2t[ocol][ks] = bf16(W2[ctrue(ks)][ocol]), K-permuted to match in-register h fragments
    const int ocol = t >> 2;
    const int ksc = t & 3;
    for (int k8 = 0; k8 < 8; ++k8) {
      bf16x8 v;
#pragma unroll
      for (int j = 0; j < 8; ++j) {
        int ks = ksc * 64 + k8 * 8 + j;
        int ct = ((ks >> 5) << 5) + (((ks >> 3) & 3) << 3) + (((ks >> 2) & 1) << 2) + (ks & 3);
        v[j] = (bf16)W2[ct * DOUT + ocol];
      }
      *(bf16x8*)&w2t[ocol * 256 + ksc * 64 + k8 * 8] = v;
    }
  }
}

__global__ __launch_bounds__(256) void pair_kernel(
    const float* __restrict__ q_equi, const float* __restrict__ k_equi,
    const float* __restrict__ Aq, const float* __restrict__ Ak,
    const bf16* __restrict__ w1t, const bf16* __restrict__ w2t,
    const float* __restrict__ b2, float* __restrict__ out)
{
  // 80KB + 80KB = exactly 160 KiB (gfx950 LDS max)
  __shared__ __align__(16) bf16 sA1[256 * KEXT];  // A-operand: W1^T rows (c-permuted) + Aq/Ak one-hot rows
  __shared__ __align__(16) bf16 sF[256 * KEXT];   // B-operand: feats per pair + one-hot cols

  const int t = threadIdx.x;
  const int bid = blockIdx.x;
  const int b = bid / (24 * 8);
  const int rem = bid % (24 * 8);
  const int qt = rem / 8, ks = rem % 8;
  const int q0 = qt * 16;
  const int k0b = ks * 48;

  const int lane = t & 63;
  const int w = t >> 6;
  const int r16 = lane & 15;
  const int g = lane >> 4;

  // ---------- prologue ----------
  {  // W1^T zone (static per block)
    const bf16* src = w1t + t * 128;
    bf16* dst = sA1 + t * KEXT;
#pragma unroll
    for (int k8 = 0; k8 < 16; ++k8)
      *(bf16x8*)&dst[k8 * 8] = *(const bf16x8*)&src[k8 * 8];
  }
  {  // Aq one-hot weight rows (block q-tile fixed): k = 128..143
    const int c = t;
    const int cs = ((c >> 5) << 5) + ((c & 4) << 2) + ((c & 24) >> 1) + (c & 3);
#pragma unroll
    for (int j4 = 0; j4 < 4; ++j4) {
      bf16x4 v;
#pragma unroll
      for (int j = 0; j < 4; ++j)
        v[j] = (bf16)Aq[(b * NQ + q0 + j4 * 4 + j) * DFF + c];
      *(bf16x4*)&sA1[cs * KEXT + 128 + j4 * 4] = v;
    }
  }
  {  // feats one-hot zone (static: local qi/ki one-hots)
    const int p = t;
    const int qi = p & 15, kil = p >> 4;
#pragma unroll
    for (int blk = 0; blk < 4; ++blk) {
      bf16x8 v;
#pragma unroll
      for (int e = 0; e < 8; ++e) {
        int j = blk * 8 + e;
        float x = (j < 16) ? ((j == qi) ? 1.f : 0.f) : (((j - 16) == kil) ? 1.f : 0.f);
        v[e] = (bf16)x;
      }
      *(bf16x8*)&sF[p * KEXT + 128 + blk * 8] = v;
    }
  }
  f32x4 b2v[4];
#pragma unroll
  for (int ot = 0; ot < 4; ++ot)
    b2v[ot] = *(const f32x4*)&b2[ot * 16 + g * 4];

  // feats-phase mapping: 4 channels x 4 qi x 4 ki per thread
  const int e4 = t & 15;
  const int g4 = (t >> 4) & 3;
  const int kiq = t >> 6;

  for (int it = 0; it < 3; ++it) {
    const int k0i = k0b + it * 16;
    // ---------- feats phase ----------
    {
      f32x4 qe[4][3], qn[4];
#pragma unroll
      for (int qii = 0; qii < 4; ++qii) {
        const int qg = b * NQ + q0 + g4 * 4 + qii;
#pragma unroll
        for (int c = 0; c < 3; ++c)
          qe[qii][c] = *(const f32x4*)&q_equi[(qg * 3 + c) * DE + e4 * 4];
        qn[qii] = qe[qii][0] * qe[qii][0] + qe[qii][1] * qe[qii][1] + qe[qii][2] * qe[qii][2];
      }
#pragma unroll
      for (int kii = 0; kii < 4; ++kii) {
        const int kil = kiq * 4 + kii;
        const int kg = b * NK + k0i + kil;
        f32x4 ke[3];
#pragma unroll
        for (int c = 0; c < 3; ++c)
          ke[c] = *(const f32x4*)&k_equi[(kg * 3 + c) * DE + e4 * 4];
        f32x4 kn = ke[0] * ke[0] + ke[1] * ke[1] + ke[2] * ke[2];
#pragma unroll
        for (int qii = 0; qii < 4; ++qii) {
          f32x4 dot = qe[qii][0] * ke[0] + qe[qii][1] * ke[1] + qe[qii][2] * ke[2];
          f32x4 d2 = qn[qii] + kn - 2.f * dot;
          const int p = kil * 16 + g4 * 4 + qii;
          bf16x4 vd, vs;
#pragma unroll
          for (int j = 0; j < 4; ++j) {
            vd[j] = (bf16)dot[j];
            float dd = d2[j] > 0.f ? d2[j] : 0.f;  // clamp cancellation -> no NaN
            vs[j] = (bf16)__builtin_amdgcn_sqrtf(dd);
          }
          *(bf16x4*)&sF[p * KEXT + e4 * 4] = vd;
          *(bf16x4*)&sF[p * KEXT + 64 + e4 * 4] = vs;
        }
      }
      // Ak one-hot weight rows for this k-tile: k = 144..159
      const int c = t;
      const int cs = ((c >> 5) << 5) + ((c & 4) << 2) + ((c & 24) >> 1) + (c & 3);
#pragma unroll
      for (int j4 = 0; j4 < 4; ++j4) {
        bf16x4 v;
#pragma unroll
        for (int j = 0; j < 4; ++j)
          v[j] = (bf16)Ak[(b * NK + k0i + j4 * 4 + j) * DFF + c];
        *(bf16x4*)&sA1[cs * KEXT + 144 + j4 * 4] = v;
      }
    }
    __syncthreads();
    // ---------- GEMM phase ----------
    {
      // B1 fragments (feats^T), register-resident across the c loop
      bf16x8 b1f[4][5];
#pragma unroll
      for (int pt = 0; pt < 4; ++pt)
#pragma unroll
        for (int kk = 0; kk < 5; ++kk)
          b1f[pt][kk] = *(const bf16x8*)&sF[((w * 4 + pt) * 16 + r16) * KEXT + kk * 32 + g * 8];

      f32x4 D2[4][4];
#pragma unroll
      for (int ot = 0; ot < 4; ++ot)
#pragma unroll
        for (int pt = 0; pt < 4; ++pt)
          D2[ot][pt] = (f32x4){0.f, 0.f, 0.f, 0.f};

#pragma unroll
      for (int kk2 = 0; kk2 < 8; ++kk2) {
        f32x4 dE[4], dO[4];
#pragma unroll
        for (int pt = 0; pt < 4; ++pt) {
          dE[pt] = (f32x4){0.f, 0.f, 0.f, 0.f};
          dO[pt] = (f32x4){0.f, 0.f, 0.f, 0.f};
        }
        const int ctE = kk2 * 2, ctO = kk2 * 2 + 1;
#pragma unroll
        for (int kk = 0; kk < 5; ++kk) {
          bf16x8 aE = *(const bf16x8*)&sA1[(ctE * 16 + r16) * KEXT + kk * 32 + g * 8];
#pragma unroll
          for (int pt = 0; pt < 4; ++pt)
            dE[pt] = __builtin_amdgcn_mfma_f32_16x16x32_bf16(aE, b1f[pt][kk], dE[pt], 0, 0, 0);
          bf16x8 aO = *(const bf16x8*)&sA1[(ctO * 16 + r16) * KEXT + kk * 32 + g * 8];
#pragma unroll
          for (int pt = 0; pt < 4; ++pt)
            dO[pt] = __builtin_amdgcn_mfma_f32_16x16x32_bf16(aO, b1f[pt][kk], dO[pt], 0, 0, 0);
        }
        bf16x8 a2[4];
#pragma unroll
        for (int ot = 0; ot < 4; ++ot)
          a2[ot] = *(const bf16x8*)&w2t[(ot * 16 + r16) * 256 + kk2 * 32 + g * 8];
#pragma unroll
        for (int pt = 0; pt < 4; ++pt) {
          bf16x8 b2f;  // silu(z) in-register -> GEMM2 B-fragment (no LDS round-trip)
#pragma unroll
          for (int r = 0; r < 4; ++r) {
            float zE = dE[pt][r];
            float sE = zE * __builtin_amdgcn_rcpf(1.f + __builtin_amdgcn_exp2f(zE * -1.44269504f));
            b2f[r] = (bf16)sE;
            float zO = dO[pt][r];
            float sO = zO * __builtin_amdgcn_rcpf(1.f + __builtin_amdgcn_exp2f(zO * -1.44269504f));
            b2f[4 + r] = (bf16)sO;
          }
#pragma unroll
          for (int ot = 0; ot < 4; ++ot)
            D2[ot][pt] = __builtin_amdgcn_mfma_f32_16x16x32_bf16(a2[ot], b2f, D2[ot][pt], 0, 0, 0);
        }
      }
      // store out^T fragments: lane holds 4 consecutive ocol for its (q,k)
#pragma unroll
      for (int pt = 0; pt < 4; ++pt) {
        const int kg = k0i + w * 4 + pt;
        float* op = out + ((b * NQ + q0 + r16) * NK + kg) * 64 + g * 4;
#pragma unroll
        for (int ot = 0; ot < 4; ++ot) {
          f32x4 v = D2[ot][pt] + b2v[ot];
          *(f32x4*)&op[ot * 16] = v;
        }
      }
    }
    __syncthreads();
  }
}

extern "C" void kernel_launch(void* const* d_in, const int* in_sizes, int n_in,
                              void* d_out, int out_size, void* d_ws, size_t ws_size,
                              hipStream_t stream) {
  const float* q_equi = (const float*)d_in[0];
  const float* q_inv = (const float*)d_in[1];
  const float* k_equi = (const float*)d_in[2];
  const float* k_inv = (const float*)d_in[3];
  const float* Wq = (const float*)d_in[4];
  const float* bq = (const float*)d_in[5];
  const float* Wk = (const float*)d_in[6];
  const float* bk = (const float*)d_in[7];
  const float* W1 = (const float*)d_in[8];
  const float* b1 = (const float*)d_in[9];
  const float* W2 = (const float*)d_in[10];
  const float* b2 = (const float*)d_in[11];
  char* ws = (char*)d_ws;
  float* Aq = (float*)(ws + WS_AQ);
  float* Ak = (float*)(ws + WS_AK);
  bf16* w1t = (bf16*)(ws + WS_W1T);
  bf16* w2t = (bf16*)(ws + WS_W2T);
  float* out = (float*)d_out;

  prep_kernel<<<2 * NB * NQ + 2, 256, 0, stream>>>(q_inv, k_inv, Wq, bq, Wk, bk, W1, b1, W2,
                                                   Aq, Ak, w1t, w2t);
  pair_kernel<<<NB * 24 * 8, 256, 0, stream>>>(q_equi, k_equi, Aq, Ak, w1t, w2t, b2, out);
}